// Round 12
// baseline (343.880 us; speedup 1.0000x reference)
//
#include <hip/hip_runtime.h>

#define B_    4
#define N_    1024
#define FIN   128
#define FOUT  256
#define NH    8
#define ND    32
#define NSL   0.2f
#define LOG2E 1.44269504088896340736f

typedef _Float16 half8 __attribute__((ext_vector_type(8)));
typedef __fp16 fp16x2 __attribute__((ext_vector_type(2)));
typedef float f32x4 __attribute__((ext_vector_type(4)));

// ---- kAB: blocks [0,adjBlocks): bit-pack adj; rest: g=h@W MFMA (W f16-converted
// into padded LDS per block -> no precursor kernel), el/er via LDS combine.
__global__ __launch_bounds__(256) void gat_kAB(
    const int* __restrict__ adj, unsigned long long* __restrict__ adjb64,
    const float* __restrict__ W, const float* __restrict__ h,
    const float* __restrict__ a_vec, _Float16* __restrict__ g16,
    float* __restrict__ elt, float* __restrict__ ert,
    int adjBlocks, int reps)
{
  __shared__ _Float16 h16s[16][136];    // pad 272B: <=2-way on b128
  __shared__ _Float16 wt16s[64][136];
  __shared__ float elp[4][16], erp[4][16];

  const int t = threadIdx.x;

  if ((int)blockIdx.x < adjBlocks) {    // ---- adj bit-pack branch ----
    const int lane = t & 63;
    const int gw = (blockIdx.x * 256 + t) >> 6;
    const size_t base0 = (size_t)gw * 1024;
#pragma unroll 1
    for (int rep = 0; rep < reps; ++rep) {
      asm volatile("" ::: "memory");
#pragma unroll
      for (int it = 0; it < 16; ++it) {
        const size_t base = base0 + it * 64;
        const unsigned long long m = __ballot(adj[base + lane] != 0);
        if (lane == 0) adjb64[base >> 6] = m;
      }
    }
    return;
  }

  // ---- gemm branch ----
  const int gb = blockIdx.x - adjBlocks;
  const int fq = gb & 3;
  const int nt = gb >> 2;
  const int n0 = nt * 16;
  const int b = n0 >> 10, nn = n0 & 1023;
  const int fbase = fq * 64;

  const int wv = t >> 6, lane = t & 63;
  const int li = lane & 15, kg = lane >> 4;
  const int head = fq * 2 + (wv >> 1);
  const int hb   = b * NH + head;
  const int fi0  = (wv & 1) * 16;

#pragma unroll 1
  for (int rep = 0; rep < reps; ++rep) {
    asm volatile("" ::: "memory");
    {   // stage h rows n0..n0+15 (f32 -> f16)
      const int hr = t >> 4, hk = (t & 15) * 8;
      const float4 v0 = *(const float4*)&h[(size_t)(n0 + hr) * FIN + hk];
      const float4 v1 = *(const float4*)&h[(size_t)(n0 + hr) * FIN + hk + 4];
      half8 o;
      o[0]=(_Float16)v0.x; o[1]=(_Float16)v0.y; o[2]=(_Float16)v0.z; o[3]=(_Float16)v0.w;
      o[4]=(_Float16)v1.x; o[5]=(_Float16)v1.y; o[6]=(_Float16)v1.z; o[7]=(_Float16)v1.w;
      *(half8*)&h16s[hr][hk] = o;
    }
    {   // stage W^T slice [fbase..fbase+63][0..127] (f32 -> f16), L2-hot
      const int fl = t & 63;
#pragma unroll 8
      for (int kk = t >> 6; kk < FIN; kk += 4)
        wt16s[fl][kk] = (_Float16)W[(size_t)kk * FOUT + fbase + fl];
    }
    __syncthreads();

    const _Float16* __restrict__ arow = &wt16s[wv * 16 + li][kg * 8];

    f32x4 acc = {0.f, 0.f, 0.f, 0.f};
#pragma unroll
    for (int ks = 0; ks < 4; ++ks) {
      const half8 Af = *(const half8*)(arow + ks * 32);
      const half8 Bf = *(const half8*)&h16s[li][ks * 32 + kg * 8];
      acc = __builtin_amdgcn_mfma_f32_16x16x32_f16(Af, Bf, acc, 0, 0, 0);
    }

    float pl = 0.f, pr = 0.f;
#pragma unroll
    for (int r = 0; r < 4; ++r) {
      const int fi = fi0 + kg * 4 + r;
      g16[((size_t)hb * ND + fi) * N_ + nn + li] = (_Float16)acc[r];
      pl += a_vec[fi] * acc[r];
      pr += a_vec[ND + fi] * acc[r];
    }
    pl *= LOG2E; pr *= LOG2E;
    pl += __shfl_xor(pl, 16); pl += __shfl_xor(pl, 32);
    pr += __shfl_xor(pr, 16); pr += __shfl_xor(pr, 32);
    if (lane < 16) { elp[wv][li] = pl; erp[wv][li] = pr; }
    __syncthreads();

    if (t < 32) {
      const int hh = t >> 4, ll = t & 15;
      const int hbw = b * NH + fq * 2 + hh;
      elt[(size_t)hbw * N_ + nn + ll] = elp[2 * hh][ll] + elp[2 * hh + 1][ll];
      ert[(size_t)hbw * N_ + nn + ll] = erp[2 * hh][ll] + erp[2 * hh + 1][ll];
    }
    __syncthreads();
  }
}

// ---- kC: block=(b,head,32-i tile), 512 thr / 8 waves; wave: 32 i x 32 f x 128 j ----
__global__ __launch_bounds__(512) void gat_kC(
    const unsigned* __restrict__ adjb, const _Float16* __restrict__ g16,
    const float* __restrict__ elt, const float* __restrict__ ert,
    float* __restrict__ out, int reps)
{
  __shared__ float er_s[N_];
  __shared__ float dpart[8][32][34];
  __shared__ float denp[8][32];

  const int t = threadIdx.x;
  const int u0 = blockIdx.x;
  const int v  = ((u0 & 7) << 7) | (u0 >> 3);   // XCD swizzle (1024 = 8*128)
  const int it   = v & 31;
  const int head = (v >> 5) & 7;
  const int b    = v >> 8;
  const int i0   = it * 32;
  const int hb   = b * NH + head;

  const int wv = t >> 6, lane = t & 63;
  const int li = lane & 15, kg = lane >> 4;

#pragma unroll 1
  for (int rep = 0; rep < reps; ++rep) {
    asm volatile("" ::: "memory");
    if (t < 256) *(float4*)&er_s[4 * t] = *(const float4*)&ert[(size_t)hb * N_ + 4 * t];
    __syncthreads();

    const float el_a = elt[(size_t)hb * N_ + i0 + li];
    const float el_b = elt[(size_t)hb * N_ + i0 + 16 + li];
    const int4* __restrict__ abA =
        (const int4*)(adjb + ((size_t)(b * N_ + i0 + li)) * 32) + wv;
    const int4* __restrict__ abB =
        (const int4*)(adjb + ((size_t)(b * N_ + i0 + 16 + li)) * 32) + wv;
    const _Float16* __restrict__ arow0 =
        g16 + ((size_t)hb * ND + li) * N_ + wv * 128 + kg * 8;
    const _Float16* __restrict__ arow1 = arow0 + (size_t)16 * N_;

    f32x4 acc0 = {0,0,0,0}, acc1 = {0,0,0,0}, accd = {0,0,0,0};
    f32x4 acc0b = {0,0,0,0}, acc1b = {0,0,0,0}, accdb = {0,0,0,0};
    const half8 ones = {(_Float16)1.f, (_Float16)1.f, (_Float16)1.f, (_Float16)1.f,
                        (_Float16)1.f, (_Float16)1.f, (_Float16)1.f, (_Float16)1.f};

    const int4 A = abA[0];
    const int4 Bm = abB[0];
    const unsigned wA[4] = {(unsigned)A.x, (unsigned)A.y, (unsigned)A.z, (unsigned)A.w};
    const unsigned wB[4] = {(unsigned)Bm.x, (unsigned)Bm.y, (unsigned)Bm.z, (unsigned)Bm.w};

#pragma unroll
    for (int u = 0; u < 4; ++u) {
      const half8 Ag0 = *(const half8*)(arow0 + u * 32);
      const half8 Ag1 = *(const half8*)(arow1 + u * 32);
      const int ks = wv * 128 + u * 32 + kg * 8;
      const float4 e0 = *(const float4*)&er_s[ks];
      const float4 e1 = *(const float4*)&er_s[ks + 4];
      const float er8[8] = {e0.x, e0.y, e0.z, e0.w, e1.x, e1.y, e1.z, e1.w};
      const unsigned sA = wA[u] >> (kg * 8);
      const unsigned sB = wB[u] >> (kg * 8);

      float pva[8], pvb[8];
#pragma unroll
      for (int e = 0; e < 8; ++e) {
        float xa = el_a + er8[e];
        float xb = el_b + er8[e];
        xa = fmaxf(xa, NSL * xa);
        xb = fmaxf(xb, NSL * xb);
        float pa, pb;
        asm("v_exp_f32 %0, %1" : "=v"(pa) : "v"(xa));
        asm("v_exp_f32 %0, %1" : "=v"(pb) : "v"(xb));
        pva[e] = ((sA >> e) & 1u) ? pa : 0.f;
        pvb[e] = ((sB >> e) & 1u) ? pb : 0.f;
      }

      union { half8 h8; unsigned uu[4]; } PA, PB;
#pragma unroll
      for (int q = 0; q < 4; ++q) {
        union { fp16x2 hh; unsigned uu; } c1, c2;
        c1.hh = __builtin_amdgcn_cvt_pkrtz(pva[2*q], pva[2*q+1]);
        c2.hh = __builtin_amdgcn_cvt_pkrtz(pvb[2*q], pvb[2*q+1]);
        PA.uu[q] = c1.uu; PB.uu[q] = c2.uu;
      }

      acc0  = __builtin_amdgcn_mfma_f32_16x16x32_f16(Ag0, PA.h8, acc0, 0, 0, 0);
      acc1  = __builtin_amdgcn_mfma_f32_16x16x32_f16(Ag1, PA.h8, acc1, 0, 0, 0);
      accd  = __builtin_amdgcn_mfma_f32_16x16x32_f16(ones, PA.h8, accd, 0, 0, 0);
      acc0b = __builtin_amdgcn_mfma_f32_16x16x32_f16(Ag0, PB.h8, acc0b, 0, 0, 0);
      acc1b = __builtin_amdgcn_mfma_f32_16x16x32_f16(Ag1, PB.h8, acc1b, 0, 0, 0);
      accdb = __builtin_amdgcn_mfma_f32_16x16x32_f16(ones, PB.h8, accdb, 0, 0, 0);
    }

#pragma unroll
    for (int r = 0; r < 4; ++r) {
      dpart[wv][4*kg + r][li]           = acc0[r];
      dpart[wv][16 + 4*kg + r][li]      = acc1[r];
      dpart[wv][4*kg + r][16 + li]      = acc0b[r];
      dpart[wv][16 + 4*kg + r][16 + li] = acc1b[r];
    }
    if (lane < 16) { denp[wv][li] = accd[0]; denp[wv][16 + li] = accdb[0]; }
    __syncthreads();

    for (int o = t; o < 1024; o += 512) {
      const int f = o & 31, ii = o >> 5;
      float s = 0.f, dn = 0.f;
#pragma unroll
      for (int p = 0; p < 8; ++p) { s += dpart[p][f][ii]; dn += denp[p][ii]; }
      float w = s / dn;
      w = fmaxf(w, NSL * w);
      out[((size_t)(b * N_ + i0 + ii)) * FOUT + head * ND + f] = w;
    }
    __syncthreads();
  }
}

extern "C" void kernel_launch(void* const* d_in, const int* in_sizes, int n_in,
                              void* d_out, int out_size, void* d_ws, size_t ws_size,
                              hipStream_t stream) {
  const float* h     = (const float*)d_in[0];
  const int*   adj   = (const int*)d_in[1];
  const float* W     = (const float*)d_in[2];
  const float* a_vec = (const float*)d_in[3];
  float* out = (float*)d_out;

  char* ws = (char*)d_ws;
  _Float16* g16  = (_Float16*)(ws);                         // 2 MB
  float*    elt  = (float*)(ws + (2u << 20));               // 128 KB
  float*    ert  = (float*)(ws + (2u << 20) + (128u << 10));
  unsigned long long* adjb64 = (unsigned long long*)(ws + (2560u << 10)); // 512 KB
  // profiling scratch
  _Float16* g16s  = (_Float16*)(ws + (3u << 20));
  float*    elts  = (float*)(ws + (5u << 20));
  float*    erts  = (float*)(ws + (5u << 20) + (128u << 10));
  unsigned long long* adjb64s = (unsigned long long*)(ws + (5632u << 10));
  float*    souts = (float*)(ws + (6u << 20));              // 4 MB

  // production: 2 dispatches
  gat_kAB<<<2048, 256, 0, stream>>>(adj, adjb64, W, h, a_vec, g16, elt, ert, 1024, 1);
  gat_kC<<<1024, 512, 0, stream>>>((const unsigned*)adjb64, g16, elt, ert, out, 1);

  // PROFILING (scratch outputs; removed next round): per-kernel visibility
  gat_kAB<<<1024, 256, 0, stream>>>(adj, adjb64s, W, h, a_vec, g16s, elts, erts, 1024, 20); // pack only
  gat_kAB<<<1024, 256, 0, stream>>>(adj, adjb64s, W, h, a_vec, g16s, elts, erts, 0, 20);    // gemm only
  gat_kC<<<1024, 512, 0, stream>>>((const unsigned*)adjb64, g16, elt, ert, souts, 16);
}

// Round 14
// 193.575 us; speedup vs baseline: 1.7765x; 1.7765x over previous
//
#include <hip/hip_runtime.h>

#define B_    4
#define N_    1024
#define FIN   128
#define FOUT  256
#define NH    8
#define ND    32
#define NSL   0.2f
#define LOG2E 1.44269504088896340736f

typedef _Float16 half8 __attribute__((ext_vector_type(8)));
typedef _Float16 h2 __attribute__((ext_vector_type(2)));
typedef __fp16 fp16x2 __attribute__((ext_vector_type(2)));
typedef float f32x4 __attribute__((ext_vector_type(4)));

static __device__ __forceinline__ unsigned bc_u(h2 v) {
  union { h2 h; unsigned u; } c; c.h = v; return c.u;
}
static __device__ __forceinline__ h2 bc_h(unsigned v) {
  union { h2 h; unsigned u; } c; c.u = v; return c.h;
}

// ---- kAB: blocks [0,1024): adj -> bytemask (0x00 keep / 0xE0 = hi-byte of f16 -512);
//      blocks [1024,2048): g = h@W MFMA with W f16-staged in LDS; el/er via LDS combine.
__global__ __launch_bounds__(256) void gat_kAB(
    const int* __restrict__ adj, unsigned char* __restrict__ mb,
    const float* __restrict__ W, const float* __restrict__ h,
    const float* __restrict__ a_vec, _Float16* __restrict__ g16,
    float* __restrict__ elt, float* __restrict__ ert)
{
  __shared__ _Float16 h16s[16][136];
  __shared__ _Float16 wt16s[64][136];
  __shared__ float elp[4][16], erp[4][16];

  const int t = threadIdx.x;

  if (blockIdx.x < 1024) {          // ---- bytemask branch (HBM-bound) ----
    const size_t base = ((size_t)blockIdx.x * 256 + t) * 16;
    unsigned w[4];
#pragma unroll
    for (int q = 0; q < 4; ++q) {
      const int4 a = *(const int4*)(adj + base + q * 4);
      w[q] = (a.x ? 0u : 0xE0u) | (a.y ? 0u : 0xE000u)
           | (a.z ? 0u : 0xE00000u) | (a.w ? 0u : 0xE0000000u);
    }
    *(uint4*)(mb + base) = make_uint4(w[0], w[1], w[2], w[3]);
    return;
  }

  // ---- gemm branch ----
  const int gb = blockIdx.x - 1024;
  const int fq = gb & 3;
  const int nt = gb >> 2;
  const int n0 = nt * 16;
  const int b = n0 >> 10, nn = n0 & 1023;
  const int fbase = fq * 64;

  const int wv = t >> 6, lane = t & 63;
  const int li = lane & 15, kg = lane >> 4;
  const int head = fq * 2 + (wv >> 1);
  const int hb   = b * NH + head;
  const int fi0  = (wv & 1) * 16;

  {   // stage h rows n0..n0+15 (f32 -> f16)
    const int hr = t >> 4, hk = (t & 15) * 8;
    const float4 v0 = *(const float4*)&h[(size_t)(n0 + hr) * FIN + hk];
    const float4 v1 = *(const float4*)&h[(size_t)(n0 + hr) * FIN + hk + 4];
    half8 o;
    o[0]=(_Float16)v0.x; o[1]=(_Float16)v0.y; o[2]=(_Float16)v0.z; o[3]=(_Float16)v0.w;
    o[4]=(_Float16)v1.x; o[5]=(_Float16)v1.y; o[6]=(_Float16)v1.z; o[7]=(_Float16)v1.w;
    *(half8*)&h16s[hr][hk] = o;
  }
  {   // stage W^T slice (f32 -> f16), L2-hot
    const int fl = t & 63;
#pragma unroll 8
    for (int kk = t >> 6; kk < FIN; kk += 4)
      wt16s[fl][kk] = (_Float16)W[(size_t)kk * FOUT + fbase + fl];
  }
  __syncthreads();

  const _Float16* __restrict__ arow = &wt16s[wv * 16 + li][kg * 8];

  f32x4 acc = {0.f, 0.f, 0.f, 0.f};
#pragma unroll
  for (int ks = 0; ks < 4; ++ks) {
    const half8 Af = *(const half8*)(arow + ks * 32);
    const half8 Bf = *(const half8*)&h16s[li][ks * 32 + kg * 8];
    acc = __builtin_amdgcn_mfma_f32_16x16x32_f16(Af, Bf, acc, 0, 0, 0);
  }

  float pl = 0.f, pr = 0.f;
#pragma unroll
  for (int r = 0; r < 4; ++r) {
    const int fi = fi0 + kg * 4 + r;
    g16[((size_t)hb * ND + fi) * N_ + nn + li] = (_Float16)acc[r];
    pl += a_vec[fi] * acc[r];
    pr += a_vec[ND + fi] * acc[r];
  }
  pl *= LOG2E; pr *= LOG2E;
  pl += __shfl_xor(pl, 16); pl += __shfl_xor(pl, 32);
  pr += __shfl_xor(pr, 16); pr += __shfl_xor(pr, 32);
  if (lane < 16) { elp[wv][li] = pl; erp[wv][li] = pr; }
  __syncthreads();

  if (t < 32) {
    const int hh = t >> 4, ll = t & 15;
    const int hbw = b * NH + fq * 2 + hh;
    elt[(size_t)hbw * N_ + nn + ll] = elp[2 * hh][ll] + elp[2 * hh + 1][ll];
    ert[(size_t)hbw * N_ + nn + ll] = erp[2 * hh][ll] + erp[2 * hh + 1][ll];
  }
}

// one packed pair: x = el2+er2+add2 (pk), lrelu (pk), exp f16 on lo + (hi>>16), repack
#define PGEN_PAIR(EL2, ERW, ADDW, OUTW)                                         \
  {                                                                             \
    h2 x = (EL2) + bc_h(ERW);                                                   \
    x = x + bc_h(ADDW);                                                         \
    h2 y = x * nsl2;                                                            \
    x = __builtin_elementwise_max(x, y);                                        \
    const unsigned xu = bc_u(x);                                                \
    const unsigned xh = xu >> 16;                                               \
    unsigned plo, phi;                                                          \
    asm("v_exp_f16 %0, %1" : "=v"(plo) : "v"(xu));                              \
    asm("v_exp_f16 %0, %1" : "=v"(phi) : "v"(xh));                              \
    (OUTW) = __builtin_amdgcn_perm(phi, plo, 0x05040100u);                      \
  }

// ---- kC: block=(b,head,32-i tile), 512 thr / 8 waves; wave: 32 i x 32 f x 128 j.
// Packed-f16 P-gen: ~4 VALU/elem (was ~7.5) -- kC was 68% VALU-issue-bound (r12 PMC).
__global__ __launch_bounds__(512) void gat_kC(
    const unsigned char* __restrict__ mb, const _Float16* __restrict__ g16,
    const float* __restrict__ elt, const float* __restrict__ ert,
    float* __restrict__ out, int reps)
{
  __shared__ _Float16 er_h[N_];
  __shared__ float dpart[8][32][34];
  __shared__ float denp[8][32];

  const int t = threadIdx.x;
  const int u0 = blockIdx.x;
  const int v  = ((u0 & 7) << 7) | (u0 >> 3);   // XCD swizzle (1024 = 8*128)
  const int it   = v & 31;
  const int head = (v >> 5) & 7;
  const int b    = v >> 8;
  const int i0   = it * 32;
  const int hb   = b * NH + head;

  const int wv = t >> 6, lane = t & 63;
  const int li = lane & 15, kg = lane >> 4;
  const h2 nsl2 = {(_Float16)NSL, (_Float16)NSL};

#pragma unroll 1
  for (int rep = 0; rep < reps; ++rep) {
    asm volatile("" ::: "memory");
    if (t < 128) {   // stage er as f16 (8 per thread)
      const float4 v0 = *(const float4*)&ert[(size_t)hb * N_ + 8 * t];
      const float4 v1 = *(const float4*)&ert[(size_t)hb * N_ + 8 * t + 4];
      half8 o;
      o[0]=(_Float16)v0.x; o[1]=(_Float16)v0.y; o[2]=(_Float16)v0.z; o[3]=(_Float16)v0.w;
      o[4]=(_Float16)v1.x; o[5]=(_Float16)v1.y; o[6]=(_Float16)v1.z; o[7]=(_Float16)v1.w;
      *(half8*)&er_h[8 * t] = o;
    }
    __syncthreads();

    const float el_a = elt[(size_t)hb * N_ + i0 + li];
    const float el_b = elt[(size_t)hb * N_ + i0 + 16 + li];
    union { fp16x2 hh; unsigned u; h2 h; } ca, cb;
    ca.hh = __builtin_amdgcn_cvt_pkrtz(el_a, el_a);
    cb.hh = __builtin_amdgcn_cvt_pkrtz(el_b, el_b);
    const h2 el2a = ca.h, el2b = cb.h;

    const uint2* __restrict__ mrowA =
        (const uint2*)(mb + ((size_t)(b * N_ + i0 + li)) * N_ + wv * 128 + kg * 8);
    const uint2* __restrict__ mrowB =
        (const uint2*)(mb + ((size_t)(b * N_ + i0 + 16 + li)) * N_ + wv * 128 + kg * 8);
    const _Float16* __restrict__ arow0 =
        g16 + ((size_t)hb * ND + li) * N_ + wv * 128 + kg * 8;
    const _Float16* __restrict__ arow1 = arow0 + (size_t)16 * N_;

    f32x4 acc0 = {0,0,0,0}, acc1 = {0,0,0,0}, accd = {0,0,0,0};
    f32x4 acc0b = {0,0,0,0}, acc1b = {0,0,0,0}, accdb = {0,0,0,0};
    const half8 ones = {(_Float16)1.f, (_Float16)1.f, (_Float16)1.f, (_Float16)1.f,
                        (_Float16)1.f, (_Float16)1.f, (_Float16)1.f, (_Float16)1.f};

    uint2 mA[4], mB[4];
#pragma unroll
    for (int u = 0; u < 4; ++u) { mA[u] = mrowA[u * 4]; mB[u] = mrowB[u * 4]; }

#pragma unroll
    for (int u = 0; u < 4; ++u) {
      const half8 Ag0 = *(const half8*)(arow0 + u * 32);
      const half8 Ag1 = *(const half8*)(arow1 + u * 32);
      const uint4 erv = *(const uint4*)&er_h[wv * 128 + u * 32 + kg * 8];
      const unsigned erw[4] = {erv.x, erv.y, erv.z, erv.w};

      unsigned addA[4], addB[4];
      addA[0] = __builtin_amdgcn_perm(0u, mA[u].x, 0x01040004u);
      addA[1] = __builtin_amdgcn_perm(0u, mA[u].x, 0x03040204u);
      addA[2] = __builtin_amdgcn_perm(0u, mA[u].y, 0x01040004u);
      addA[3] = __builtin_amdgcn_perm(0u, mA[u].y, 0x03040204u);
      addB[0] = __builtin_amdgcn_perm(0u, mB[u].x, 0x01040004u);
      addB[1] = __builtin_amdgcn_perm(0u, mB[u].x, 0x03040204u);
      addB[2] = __builtin_amdgcn_perm(0u, mB[u].y, 0x01040004u);
      addB[3] = __builtin_amdgcn_perm(0u, mB[u].y, 0x03040204u);

      union { half8 h8; unsigned uu[4]; } PA, PB;
#pragma unroll
      for (int q = 0; q < 4; ++q) {
        PGEN_PAIR(el2a, erw[q], addA[q], PA.uu[q])
        PGEN_PAIR(el2b, erw[q], addB[q], PB.uu[q])
      }

      acc0  = __builtin_amdgcn_mfma_f32_16x16x32_f16(Ag0, PA.h8, acc0, 0, 0, 0);
      acc1  = __builtin_amdgcn_mfma_f32_16x16x32_f16(Ag1, PA.h8, acc1, 0, 0, 0);
      accd  = __builtin_amdgcn_mfma_f32_16x16x32_f16(ones, PA.h8, accd, 0, 0, 0);
      acc0b = __builtin_amdgcn_mfma_f32_16x16x32_f16(Ag0, PB.h8, acc0b, 0, 0, 0);
      acc1b = __builtin_amdgcn_mfma_f32_16x16x32_f16(Ag1, PB.h8, acc1b, 0, 0, 0);
      accdb = __builtin_amdgcn_mfma_f32_16x16x32_f16(ones, PB.h8, accdb, 0, 0, 0);
    }

#pragma unroll
    for (int r = 0; r < 4; ++r) {
      dpart[wv][4*kg + r][li]           = acc0[r];
      dpart[wv][16 + 4*kg + r][li]      = acc1[r];
      dpart[wv][4*kg + r][16 + li]      = acc0b[r];
      dpart[wv][16 + 4*kg + r][16 + li] = acc1b[r];
    }
    if (lane < 16) { denp[wv][li] = accd[0]; denp[wv][16 + li] = accdb[0]; }
    __syncthreads();

    for (int o = t; o < 1024; o += 512) {
      const int f = o & 31, ii = o >> 5;
      float s = 0.f, dn = 0.f;
#pragma unroll
      for (int p = 0; p < 8; ++p) { s += dpart[p][f][ii]; dn += denp[p][ii]; }
      float w = s / dn;
      w = fmaxf(w, NSL * w);
      out[((size_t)(b * N_ + i0 + ii)) * FOUT + head * ND + f] = w;
    }
    __syncthreads();
  }
}

extern "C" void kernel_launch(void* const* d_in, const int* in_sizes, int n_in,
                              void* d_out, int out_size, void* d_ws, size_t ws_size,
                              hipStream_t stream) {
  const float* h     = (const float*)d_in[0];
  const int*   adj   = (const int*)d_in[1];
  const float* W     = (const float*)d_in[2];
  const float* a_vec = (const float*)d_in[3];
  float* out = (float*)d_out;

  char* ws = (char*)d_ws;
  _Float16* g16  = (_Float16*)(ws);                         // 2 MB
  float*    elt  = (float*)(ws + (2u << 20));               // 128 KB
  float*    ert  = (float*)(ws + (2u << 20) + (128u << 10));
  unsigned char* mbm = (unsigned char*)(ws + (3u << 20));   // 4 MB bytemask
  float*    souts = (float*)(ws + (8u << 20));              // 4 MB prof scratch

  // production
  gat_kAB<<<2048, 256, 0, stream>>>(adj, mbm, W, h, a_vec, g16, elt, ert);
  gat_kC<<<1024, 512, 0, stream>>>(mbm, g16, elt, ert, out, 1);

  // PROFILING (scratch out; removed next round): verify packed P-gen VALU delta
  gat_kC<<<1024, 512, 0, stream>>>(mbm, g16, elt, ert, souts, 10);
}

// Round 15
// 156.639 us; speedup vs baseline: 2.1954x; 1.2358x over previous
//
#include <hip/hip_runtime.h>

#define B_    4
#define N_    1024
#define FIN   128
#define FOUT  256
#define NH    8
#define ND    32
#define NSL   0.2f
#define LOG2E 1.44269504088896340736f

typedef _Float16 half8 __attribute__((ext_vector_type(8)));
typedef _Float16 h2 __attribute__((ext_vector_type(2)));
typedef __fp16 fp16x2 __attribute__((ext_vector_type(2)));
typedef float f32x4 __attribute__((ext_vector_type(4)));

static __device__ __forceinline__ unsigned bc_u(h2 v) {
  union { h2 h; unsigned u; } c; c.h = v; return c.u;
}
static __device__ __forceinline__ h2 bc_h(unsigned v) {
  union { h2 h; unsigned u; } c; c.u = v; return c.h;
}

// ---- kAB: blocks [0,1024): bit-pack adj via ballot (512KB total);
//      blocks [1024,2048): g = h@W MFMA, W f16-staged in LDS; el/er LDS combine.
__global__ __launch_bounds__(256) void gat_kAB(
    const int* __restrict__ adj, unsigned long long* __restrict__ adjb64,
    const float* __restrict__ W, const float* __restrict__ h,
    const float* __restrict__ a_vec, _Float16* __restrict__ g16,
    float* __restrict__ elt, float* __restrict__ ert)
{
  __shared__ _Float16 h16s[16][136];
  __shared__ _Float16 wt16s[64][136];
  __shared__ float elp[4][16], erp[4][16];

  const int t = threadIdx.x;

  if (blockIdx.x < 1024) {          // ---- bitmask branch (HBM-bound) ----
    const int gw = (blockIdx.x * 256 + t) >> 6;
    const int lane = t & 63;
    const size_t base0 = (size_t)gw * 1024;
#pragma unroll
    for (int it = 0; it < 16; ++it) {
      const size_t base = base0 + it * 64;
      const unsigned long long m = __ballot(adj[base + lane] != 0);
      if (lane == 0) adjb64[base >> 6] = m;
    }
    return;
  }

  // ---- gemm branch ----
  const int gb = blockIdx.x - 1024;
  const int fq = gb & 3;
  const int nt = gb >> 2;
  const int n0 = nt * 16;
  const int b = n0 >> 10, nn = n0 & 1023;
  const int fbase = fq * 64;

  const int wv = t >> 6, lane = t & 63;
  const int li = lane & 15, kg = lane >> 4;
  const int head = fq * 2 + (wv >> 1);
  const int hb   = b * NH + head;
  const int fi0  = (wv & 1) * 16;

  {   // stage h rows n0..n0+15 (f32 -> f16)
    const int hr = t >> 4, hk = (t & 15) * 8;
    const float4 v0 = *(const float4*)&h[(size_t)(n0 + hr) * FIN + hk];
    const float4 v1 = *(const float4*)&h[(size_t)(n0 + hr) * FIN + hk + 4];
    half8 o;
    o[0]=(_Float16)v0.x; o[1]=(_Float16)v0.y; o[2]=(_Float16)v0.z; o[3]=(_Float16)v0.w;
    o[4]=(_Float16)v1.x; o[5]=(_Float16)v1.y; o[6]=(_Float16)v1.z; o[7]=(_Float16)v1.w;
    *(half8*)&h16s[hr][hk] = o;
  }
  {   // stage W^T slice (f32 -> f16), L2-hot
    const int fl = t & 63;
#pragma unroll 8
    for (int kk = t >> 6; kk < FIN; kk += 4)
      wt16s[fl][kk] = (_Float16)W[(size_t)kk * FOUT + fbase + fl];
  }
  __syncthreads();

  const _Float16* __restrict__ arow = &wt16s[wv * 16 + li][kg * 8];

  f32x4 acc = {0.f, 0.f, 0.f, 0.f};
#pragma unroll
  for (int ks = 0; ks < 4; ++ks) {
    const half8 Af = *(const half8*)(arow + ks * 32);
    const half8 Bf = *(const half8*)&h16s[li][ks * 32 + kg * 8];
    acc = __builtin_amdgcn_mfma_f32_16x16x32_f16(Af, Bf, acc, 0, 0, 0);
  }

  float pl = 0.f, pr = 0.f;
#pragma unroll
  for (int r = 0; r < 4; ++r) {
    const int fi = fi0 + kg * 4 + r;
    g16[((size_t)hb * ND + fi) * N_ + nn + li] = (_Float16)acc[r];
    pl += a_vec[fi] * acc[r];
    pr += a_vec[ND + fi] * acc[r];
  }
  pl *= LOG2E; pr *= LOG2E;
  pl += __shfl_xor(pl, 16); pl += __shfl_xor(pl, 32);
  pr += __shfl_xor(pr, 16); pr += __shfl_xor(pr, 32);
  if (lane < 16) { elp[wv][li] = pl; erp[wv][li] = pr; }
  __syncthreads();

  if (t < 32) {
    const int hh = t >> 4, ll = t & 15;
    const int hbw = b * NH + fq * 2 + hh;
    elt[(size_t)hbw * N_ + nn + ll] = elp[2 * hh][ll] + elp[2 * hh + 1][ll];
    ert[(size_t)hbw * N_ + nn + ll] = erp[2 * hh][ll] + erp[2 * hh + 1][ll];
  }
}

// packed pair: x = el2+er2 (pk), lrelu (pk), exp f16 lo + hi, repack, AND-mask
#define PGEN_PAIR(EL2, ERW, MAW, OUTW)                                          \
  {                                                                             \
    h2 x = (EL2) + bc_h(ERW);                                                   \
    h2 y = x * nsl2;                                                            \
    x = __builtin_elementwise_max(x, y);                                        \
    const unsigned xu = bc_u(x);                                                \
    const unsigned xh = xu >> 16;                                               \
    unsigned plo, phi;                                                          \
    asm("v_exp_f16 %0, %1" : "=v"(plo) : "v"(xu));                              \
    asm("v_exp_f16 %0, %1" : "=v"(phi) : "v"(xh));                              \
    (OUTW) = __builtin_amdgcn_perm(phi, plo, 0x05040100u) & (MAW);              \
  }

// ---- kC: block=(b,head,64-i tile), 1024 thr / 16 waves (8 j-splits x 2 i-halves).
// Per wave: 32 i x 32 f x 128 j (r14-verified structure). Bitmask + 256-entry
// LDS LUT (byte -> 4 AND-words). 64-i block halves g16 L2 traffic vs 32-i.
__global__ __launch_bounds__(1024) void gat_kC(
    const unsigned* __restrict__ adjb, const _Float16* __restrict__ g16,
    const float* __restrict__ elt, const float* __restrict__ ert,
    float* __restrict__ out, int reps)
{
  __shared__ _Float16 er_h[N_];          // 2 KB
  __shared__ float dpart[8][32][68];     // 69.6 KB
  __shared__ float denp[8][64];          // 2 KB
  __shared__ uint4 lutm[256];            // 4 KB

  const int t = threadIdx.x;
  const int u0 = blockIdx.x;
  const int v  = ((u0 & 7) << 6) | (u0 >> 3);   // XCD swizzle (512 = 8*64)
  const int it   = v & 15;
  const int head = (v >> 4) & 7;
  const int b    = v >> 7;
  const int i0   = it * 64;
  const int hb   = b * NH + head;

  const int w16 = t >> 6;                // wave 0..15
  const int wv  = w16 >> 1;              // j-split 0..7
  const int ih  = w16 & 1;               // i-half
  const int lane = t & 63;
  const int li = lane & 15, kg = lane >> 4, kg8 = kg * 8;
  const h2 nsl2 = {(_Float16)NSL, (_Float16)NSL};

  if (t < 256) {                         // build AND-mask LUT (once)
    const unsigned m = t;
    uint4 e;
    e.x = ((m &   1u) ? 0xFFFFu : 0u) | ((m &   2u) ? 0xFFFF0000u : 0u);
    e.y = ((m &   4u) ? 0xFFFFu : 0u) | ((m &   8u) ? 0xFFFF0000u : 0u);
    e.z = ((m &  16u) ? 0xFFFFu : 0u) | ((m &  32u) ? 0xFFFF0000u : 0u);
    e.w = ((m &  64u) ? 0xFFFFu : 0u) | ((m & 128u) ? 0xFFFF0000u : 0u);
    lutm[t] = e;
  }

#pragma unroll 1
  for (int rep = 0; rep < reps; ++rep) {
    asm volatile("" ::: "memory");
    if (t < 128) {   // stage er as f16
      const float4 v0 = *(const float4*)&ert[(size_t)hb * N_ + 8 * t];
      const float4 v1 = *(const float4*)&ert[(size_t)hb * N_ + 8 * t + 4];
      half8 o;
      o[0]=(_Float16)v0.x; o[1]=(_Float16)v0.y; o[2]=(_Float16)v0.z; o[3]=(_Float16)v0.w;
      o[4]=(_Float16)v1.x; o[5]=(_Float16)v1.y; o[6]=(_Float16)v1.z; o[7]=(_Float16)v1.w;
      *(half8*)&er_h[8 * t] = o;
    }
    __syncthreads();   // covers LUT (rep 0) + er staging

    const int rowA = i0 + ih * 32 + li;
    const int rowB = rowA + 16;
    const float el_a = elt[(size_t)hb * N_ + rowA];
    const float el_b = elt[(size_t)hb * N_ + rowB];
    union { fp16x2 hh; unsigned u; h2 h; } ca, cb;
    ca.hh = __builtin_amdgcn_cvt_pkrtz(el_a, el_a);
    cb.hh = __builtin_amdgcn_cvt_pkrtz(el_b, el_b);
    const h2 el2a = ca.h, el2b = cb.h;

    const int4 A  = ((const int4*)(adjb + (size_t)(b * N_ + rowA) * 32))[wv];
    const int4 Bm = ((const int4*)(adjb + (size_t)(b * N_ + rowB) * 32))[wv];
    const unsigned wA[4] = {(unsigned)A.x, (unsigned)A.y, (unsigned)A.z, (unsigned)A.w};
    const unsigned wB[4] = {(unsigned)Bm.x, (unsigned)Bm.y, (unsigned)Bm.z, (unsigned)Bm.w};

    const _Float16* __restrict__ arow0 =
        g16 + ((size_t)hb * ND + li) * N_ + wv * 128 + kg8;
    const _Float16* __restrict__ arow1 = arow0 + (size_t)16 * N_;

    f32x4 acc0 = {0,0,0,0}, acc1 = {0,0,0,0}, accd = {0,0,0,0};
    f32x4 acc0b = {0,0,0,0}, acc1b = {0,0,0,0}, accdb = {0,0,0,0};
    const half8 ones = {(_Float16)1.f, (_Float16)1.f, (_Float16)1.f, (_Float16)1.f,
                        (_Float16)1.f, (_Float16)1.f, (_Float16)1.f, (_Float16)1.f};

#pragma unroll
    for (int u = 0; u < 4; ++u) {
      const half8 Ag0 = *(const half8*)(arow0 + u * 32);
      const half8 Ag1 = *(const half8*)(arow1 + u * 32);
      const uint4 erv = *(const uint4*)&er_h[wv * 128 + u * 32 + kg8];
      const unsigned erw[4] = {erv.x, erv.y, erv.z, erv.w};

      const uint4 mawA = lutm[(wA[u] >> kg8) & 0xFFu];
      const uint4 mawB = lutm[(wB[u] >> kg8) & 0xFFu];
      const unsigned maA[4] = {mawA.x, mawA.y, mawA.z, mawA.w};
      const unsigned maB[4] = {mawB.x, mawB.y, mawB.z, mawB.w};

      union { half8 h8; unsigned uu[4]; } PA, PB;
#pragma unroll
      for (int q = 0; q < 4; ++q) {
        PGEN_PAIR(el2a, erw[q], maA[q], PA.uu[q])
        PGEN_PAIR(el2b, erw[q], maB[q], PB.uu[q])
      }

      acc0  = __builtin_amdgcn_mfma_f32_16x16x32_f16(Ag0, PA.h8, acc0, 0, 0, 0);
      acc1  = __builtin_amdgcn_mfma_f32_16x16x32_f16(Ag1, PA.h8, acc1, 0, 0, 0);
      accd  = __builtin_amdgcn_mfma_f32_16x16x32_f16(ones, PA.h8, accd, 0, 0, 0);
      acc0b = __builtin_amdgcn_mfma_f32_16x16x32_f16(Ag0, PB.h8, acc0b, 0, 0, 0);
      acc1b = __builtin_amdgcn_mfma_f32_16x16x32_f16(Ag1, PB.h8, acc1b, 0, 0, 0);
      accdb = __builtin_amdgcn_mfma_f32_16x16x32_f16(ones, PB.h8, accdb, 0, 0, 0);
    }

    const int ci = ih * 32 + li;
#pragma unroll
    for (int r = 0; r < 4; ++r) {
      dpart[wv][4*kg + r][ci]           = acc0[r];
      dpart[wv][16 + 4*kg + r][ci]      = acc1[r];
      dpart[wv][4*kg + r][16 + ci]      = acc0b[r];
      dpart[wv][16 + 4*kg + r][16 + ci] = acc1b[r];
    }
    if (lane < 16) { denp[wv][ci] = accd[0]; denp[wv][16 + ci] = accdb[0]; }
    __syncthreads();

    for (int o = t; o < 2048; o += 1024) {
      const int f = o & 31, ii = o >> 5;     // ii 0..63
      float s = 0.f, dn = 0.f;
#pragma unroll
      for (int p = 0; p < 8; ++p) { s += dpart[p][f][ii]; dn += denp[p][ii]; }
      float w = s / dn;
      w = fmaxf(w, NSL * w);
      out[((size_t)(b * N_ + i0 + ii)) * FOUT + head * ND + f] = w;
    }
    __syncthreads();
  }
}

extern "C" void kernel_launch(void* const* d_in, const int* in_sizes, int n_in,
                              void* d_out, int out_size, void* d_ws, size_t ws_size,
                              hipStream_t stream) {
  const float* h     = (const float*)d_in[0];
  const int*   adj   = (const int*)d_in[1];
  const float* W     = (const float*)d_in[2];
  const float* a_vec = (const float*)d_in[3];
  float* out = (float*)d_out;

  char* ws = (char*)d_ws;
  _Float16* g16  = (_Float16*)(ws);                         // 2 MB
  float*    elt  = (float*)(ws + (2u << 20));               // 128 KB
  float*    ert  = (float*)(ws + (2u << 20) + (128u << 10));
  unsigned long long* adjb64 = (unsigned long long*)(ws + (2560u << 10)); // 512 KB
  float*    souts = (float*)(ws + (8u << 20));              // 16 MB prof scratch

  // production
  gat_kAB<<<2048, 256, 0, stream>>>(adj, adjb64, W, h, a_vec, g16, elt, ert);
  gat_kC<<<512, 1024, 0, stream>>>((const unsigned*)adjb64, g16, elt, ert, out, 1);

  // PROFILING (scratch out; removed next round): verify L2/LUT theory
  gat_kC<<<512, 1024, 0, stream>>>((const unsigned*)adjb64, g16, elt, ert, souts, 10);
}

// Round 16
// 33.191 us; speedup vs baseline: 10.3606x; 4.7193x over previous
//
#include <hip/hip_runtime.h>

#define B_    4
#define N_    1024
#define FIN   128
#define FOUT  256
#define NH    8
#define ND    32
#define NSL   0.2f
#define LOG2E 1.44269504088896340736f

typedef _Float16 half8 __attribute__((ext_vector_type(8)));
typedef _Float16 h2 __attribute__((ext_vector_type(2)));
typedef __fp16 fp16x2 __attribute__((ext_vector_type(2)));
typedef float f32x4 __attribute__((ext_vector_type(4)));

static __device__ __forceinline__ unsigned bc_u(h2 v) {
  union { h2 h; unsigned u; } c; c.h = v; return c.u;
}
static __device__ __forceinline__ h2 bc_h(unsigned v) {
  union { h2 h; unsigned u; } c; c.u = v; return c.h;
}

// ---- kAB: blocks [0,1024): bit-pack adj via ballot (512KB total);
//      blocks [1024,2048): g = h@W MFMA, W f16-staged in LDS; el/er LDS combine.
__global__ __launch_bounds__(256) void gat_kAB(
    const int* __restrict__ adj, unsigned long long* __restrict__ adjb64,
    const float* __restrict__ W, const float* __restrict__ h,
    const float* __restrict__ a_vec, _Float16* __restrict__ g16,
    float* __restrict__ elt, float* __restrict__ ert)
{
  __shared__ _Float16 h16s[16][136];
  __shared__ _Float16 wt16s[64][136];
  __shared__ float elp[4][16], erp[4][16];

  const int t = threadIdx.x;

  if (blockIdx.x < 1024) {          // ---- bitmask branch (HBM-bound) ----
    const int gw = (blockIdx.x * 256 + t) >> 6;
    const int lane = t & 63;
    const size_t base0 = (size_t)gw * 1024;
#pragma unroll
    for (int it = 0; it < 16; ++it) {
      const size_t base = base0 + it * 64;
      const unsigned long long m = __ballot(adj[base + lane] != 0);
      if (lane == 0) adjb64[base >> 6] = m;
    }
    return;
  }

  // ---- gemm branch ----
  const int gb = blockIdx.x - 1024;
  const int fq = gb & 3;
  const int nt = gb >> 2;
  const int n0 = nt * 16;
  const int b = n0 >> 10, nn = n0 & 1023;
  const int fbase = fq * 64;

  const int wv = t >> 6, lane = t & 63;
  const int li = lane & 15, kg = lane >> 4;
  const int head = fq * 2 + (wv >> 1);
  const int hb   = b * NH + head;
  const int fi0  = (wv & 1) * 16;

  {   // stage h rows n0..n0+15 (f32 -> f16)
    const int hr = t >> 4, hk = (t & 15) * 8;
    const float4 v0 = *(const float4*)&h[(size_t)(n0 + hr) * FIN + hk];
    const float4 v1 = *(const float4*)&h[(size_t)(n0 + hr) * FIN + hk + 4];
    half8 o;
    o[0]=(_Float16)v0.x; o[1]=(_Float16)v0.y; o[2]=(_Float16)v0.z; o[3]=(_Float16)v0.w;
    o[4]=(_Float16)v1.x; o[5]=(_Float16)v1.y; o[6]=(_Float16)v1.z; o[7]=(_Float16)v1.w;
    *(half8*)&h16s[hr][hk] = o;
  }
  {   // stage W^T slice (f32 -> f16), L2-hot
    const int fl = t & 63;
#pragma unroll 8
    for (int kk = t >> 6; kk < FIN; kk += 4)
      wt16s[fl][kk] = (_Float16)W[(size_t)kk * FOUT + fbase + fl];
  }
  __syncthreads();

  const _Float16* __restrict__ arow = &wt16s[wv * 16 + li][kg * 8];

  f32x4 acc = {0.f, 0.f, 0.f, 0.f};
#pragma unroll
  for (int ks = 0; ks < 4; ++ks) {
    const half8 Af = *(const half8*)(arow + ks * 32);
    const half8 Bf = *(const half8*)&h16s[li][ks * 32 + kg * 8];
    acc = __builtin_amdgcn_mfma_f32_16x16x32_f16(Af, Bf, acc, 0, 0, 0);
  }

  float pl = 0.f, pr = 0.f;
#pragma unroll
  for (int r = 0; r < 4; ++r) {
    const int fi = fi0 + kg * 4 + r;
    g16[((size_t)hb * ND + fi) * N_ + nn + li] = (_Float16)acc[r];
    pl += a_vec[fi] * acc[r];
    pr += a_vec[ND + fi] * acc[r];
  }
  pl *= LOG2E; pr *= LOG2E;
  pl += __shfl_xor(pl, 16); pl += __shfl_xor(pl, 32);
  pr += __shfl_xor(pr, 16); pr += __shfl_xor(pr, 32);
  if (lane < 16) { elp[wv][li] = pl; erp[wv][li] = pr; }
  __syncthreads();

  if (t < 32) {
    const int hh = t >> 4, ll = t & 15;
    const int hbw = b * NH + fq * 2 + hh;
    elt[(size_t)hbw * N_ + nn + ll] = elp[2 * hh][ll] + elp[2 * hh + 1][ll];
    ert[(size_t)hbw * N_ + nn + ll] = erp[2 * hh][ll] + erp[2 * hh + 1][ll];
  }
}

// AND-word from 2 adj bits: sbfe sign-extends each bit to 0x0/0xFFFFFFFF;
// perm packs lo16(lo) | hi16(hi). Pure VALU -- replaces the r15 LDS LUT
// whose random-index uint4 reads tripled bank conflicts.
#define MASKW(SH, Q)                                                            \
  __builtin_amdgcn_perm(                                                        \
      (unsigned)__builtin_amdgcn_sbfe((int)(SH), 2*(Q)+1, 1),                   \
      (unsigned)__builtin_amdgcn_sbfe((int)(SH), 2*(Q), 1), 0x07060100u)

// packed pair: x = el2+er2 (pk), lrelu (pk), exp f16 lo + hi, repack, AND-mask
#define PGEN_PAIR(EL2, ERW, MAW, OUTW)                                          \
  {                                                                             \
    h2 x = (EL2) + bc_h(ERW);                                                   \
    h2 y = x * nsl2;                                                            \
    x = __builtin_elementwise_max(x, y);                                        \
    const unsigned xu = bc_u(x);                                                \
    const unsigned xh = xu >> 16;                                               \
    unsigned plo, phi;                                                          \
    asm("v_exp_f16 %0, %1" : "=v"(plo) : "v"(xu));                              \
    asm("v_exp_f16 %0, %1" : "=v"(phi) : "v"(xh));                              \
    (OUTW) = __builtin_amdgcn_perm(phi, plo, 0x05040100u) & (MAW);              \
  }

// ---- kC: block=(b,head,64-i tile), 1024 thr / 16 waves (8 j-splits x 2 i-halves).
// Per wave: 32 i x 32 f x 128 j. Packed-f16 P-gen, pure-VALU masking.
__global__ __launch_bounds__(1024) void gat_kC(
    const unsigned* __restrict__ adjb, const _Float16* __restrict__ g16,
    const float* __restrict__ elt, const float* __restrict__ ert,
    float* __restrict__ out)
{
  __shared__ _Float16 er_h[N_];          // 2 KB
  __shared__ float dpart[8][32][68];     // 69.6 KB
  __shared__ float denp[8][64];          // 2 KB

  const int t = threadIdx.x;
  const int u0 = blockIdx.x;
  const int v  = ((u0 & 7) << 6) | (u0 >> 3);   // XCD swizzle (512 = 8*64)
  const int it   = v & 15;
  const int head = (v >> 4) & 7;
  const int b    = v >> 7;
  const int i0   = it * 64;
  const int hb   = b * NH + head;

  const int w16 = t >> 6;                // wave 0..15
  const int wv  = w16 >> 1;              // j-split 0..7
  const int ih  = w16 & 1;               // i-half
  const int lane = t & 63;
  const int li = lane & 15, kg = lane >> 4, kg8 = kg * 8;
  const h2 nsl2 = {(_Float16)NSL, (_Float16)NSL};

  // stage er as f16: all 1024 threads, one element each (parallel, low latency)
  er_h[t] = (_Float16)ert[(size_t)hb * N_ + t];
  __syncthreads();

  const int rowA = i0 + ih * 32 + li;
  const int rowB = rowA + 16;
  const float el_a = elt[(size_t)hb * N_ + rowA];
  const float el_b = elt[(size_t)hb * N_ + rowB];
  union { fp16x2 hh; unsigned u; h2 h; } ca, cb;
  ca.hh = __builtin_amdgcn_cvt_pkrtz(el_a, el_a);
  cb.hh = __builtin_amdgcn_cvt_pkrtz(el_b, el_b);
  const h2 el2a = ca.h, el2b = cb.h;

  const int4 A  = ((const int4*)(adjb + (size_t)(b * N_ + rowA) * 32))[wv];
  const int4 Bm = ((const int4*)(adjb + (size_t)(b * N_ + rowB) * 32))[wv];
  const unsigned wA[4] = {(unsigned)A.x, (unsigned)A.y, (unsigned)A.z, (unsigned)A.w};
  const unsigned wB[4] = {(unsigned)Bm.x, (unsigned)Bm.y, (unsigned)Bm.z, (unsigned)Bm.w};

  const _Float16* __restrict__ arow0 =
      g16 + ((size_t)hb * ND + li) * N_ + wv * 128 + kg8;
  const _Float16* __restrict__ arow1 = arow0 + (size_t)16 * N_;

  f32x4 acc0 = {0,0,0,0}, acc1 = {0,0,0,0}, accd = {0,0,0,0};
  f32x4 acc0b = {0,0,0,0}, acc1b = {0,0,0,0}, accdb = {0,0,0,0};
  const half8 ones = {(_Float16)1.f, (_Float16)1.f, (_Float16)1.f, (_Float16)1.f,
                      (_Float16)1.f, (_Float16)1.f, (_Float16)1.f, (_Float16)1.f};

#pragma unroll
  for (int u = 0; u < 4; ++u) {
    const half8 Ag0 = *(const half8*)(arow0 + u * 32);
    const half8 Ag1 = *(const half8*)(arow1 + u * 32);
    const uint4 erv = *(const uint4*)&er_h[wv * 128 + u * 32 + kg8];
    const unsigned erw[4] = {erv.x, erv.y, erv.z, erv.w};

    const unsigned shA = wA[u] >> kg8;
    const unsigned shB = wB[u] >> kg8;

    union { half8 h8; unsigned uu[4]; } PA, PB;
#pragma unroll
    for (int q = 0; q < 4; ++q) {
      const unsigned maA = MASKW(shA, q);
      const unsigned maB = MASKW(shB, q);
      PGEN_PAIR(el2a, erw[q], maA, PA.uu[q])
      PGEN_PAIR(el2b, erw[q], maB, PB.uu[q])
    }

    acc0  = __builtin_amdgcn_mfma_f32_16x16x32_f16(Ag0, PA.h8, acc0, 0, 0, 0);
    acc1  = __builtin_amdgcn_mfma_f32_16x16x32_f16(Ag1, PA.h8, acc1, 0, 0, 0);
    accd  = __builtin_amdgcn_mfma_f32_16x16x32_f16(ones, PA.h8, accd, 0, 0, 0);
    acc0b = __builtin_amdgcn_mfma_f32_16x16x32_f16(Ag0, PB.h8, acc0b, 0, 0, 0);
    acc1b = __builtin_amdgcn_mfma_f32_16x16x32_f16(Ag1, PB.h8, acc1b, 0, 0, 0);
    accdb = __builtin_amdgcn_mfma_f32_16x16x32_f16(ones, PB.h8, accdb, 0, 0, 0);
  }

  const int ci = ih * 32 + li;
#pragma unroll
  for (int r = 0; r < 4; ++r) {
    dpart[wv][4*kg + r][ci]           = acc0[r];
    dpart[wv][16 + 4*kg + r][ci]      = acc1[r];
    dpart[wv][4*kg + r][16 + ci]      = acc0b[r];
    dpart[wv][16 + 4*kg + r][16 + ci] = acc1b[r];
  }
  if (lane < 16) { denp[wv][ci] = accd[0]; denp[wv][16 + ci] = accdb[0]; }
  __syncthreads();

  for (int o = t; o < 2048; o += 1024) {
    const int f = o & 31, ii = o >> 5;     // ii 0..63
    float s = 0.f, dn = 0.f;
#pragma unroll
    for (int p = 0; p < 8; ++p) { s += dpart[p][f][ii]; dn += denp[p][ii]; }
    float w = s / dn;
    w = fmaxf(w, NSL * w);
    out[((size_t)(b * N_ + i0 + ii)) * FOUT + head * ND + f] = w;
  }
}

extern "C" void kernel_launch(void* const* d_in, const int* in_sizes, int n_in,
                              void* d_out, int out_size, void* d_ws, size_t ws_size,
                              hipStream_t stream) {
  const float* h     = (const float*)d_in[0];
  const int*   adj   = (const int*)d_in[1];
  const float* W     = (const float*)d_in[2];
  const float* a_vec = (const float*)d_in[3];
  float* out = (float*)d_out;

  char* ws = (char*)d_ws;
  _Float16* g16  = (_Float16*)(ws);                         // 2 MB
  float*    elt  = (float*)(ws + (2u << 20));               // 128 KB
  float*    ert  = (float*)(ws + (2u << 20) + (128u << 10));
  unsigned long long* adjb64 = (unsigned long long*)(ws + (2560u << 10)); // 512 KB

  gat_kAB<<<2048, 256, 0, stream>>>(adj, adjb64, W, h, a_vec, g16, elt, ert);
  gat_kC<<<512, 1024, 0, stream>>>((const unsigned*)adjb64, g16, elt, ert, out);
}